// Round 1
// baseline (299.245 us; speedup 1.0000x reference)
//
#include <hip/hip_runtime.h>
#include <hip/hip_bf16.h>
#include <cstdint>

typedef __bf16 bf16x8 __attribute__((ext_vector_type(8)));
typedef float f32x4 __attribute__((ext_vector_type(4)));

// ---------- helpers ----------
__device__ __forceinline__ unsigned short f2bf(float f) {
  union { float f; uint32_t u; } a; a.f = f;
  uint32_t r = a.u + 0x7fffu + ((a.u >> 16) & 1u);
  return (unsigned short)(r >> 16);
}
__device__ __forceinline__ float bf2f(unsigned short b) {
  union { uint32_t u; float f; } a; a.u = ((uint32_t)b) << 16;
  return a.f;
}
__device__ __forceinline__ void gload_lds16(const unsigned short* g, unsigned short* l) {
  __builtin_amdgcn_global_load_lds(
      (const __attribute__((address_space(1))) void*)g,
      (__attribute__((address_space(3))) void*)l, 16, 0, 0);
}

// ---------- cast kernels ----------
// x: 8,388,608 fp32 -> bf16. 8 elems/thread, grid 4096 x 256.
__global__ void cast_x_kernel(const float* __restrict__ x, unsigned short* __restrict__ xb) {
  size_t i = ((size_t)blockIdx.x * 256 + threadIdx.x) * 8;
  float4 a = *(const float4*)(x + i);
  float4 b = *(const float4*)(x + i + 4);
  uint4 o;
  o.x = (uint32_t)f2bf(a.x) | ((uint32_t)f2bf(a.y) << 16);
  o.y = (uint32_t)f2bf(a.z) | ((uint32_t)f2bf(a.w) << 16);
  o.z = (uint32_t)f2bf(b.x) | ((uint32_t)f2bf(b.y) << 16);
  o.w = (uint32_t)f2bf(b.z) | ((uint32_t)f2bf(b.w) << 16);
  *(uint4*)(xb + i) = o;
}

// W[3][1024][1024] fp32 -> Wt[3][e][d] bf16 (transpose last two dims).
// grid (32,32,3), block (32,8)
__global__ void cast_w_kernel(const float* __restrict__ W, unsigned short* __restrict__ Wt) {
  __shared__ float tile[32][33];
  const int z = blockIdx.z;
  const float* Wz = W + (size_t)z * 1024 * 1024;
  unsigned short* Wtz = Wt + (size_t)z * 1024 * 1024;
  const int x0 = blockIdx.x * 32, y0 = blockIdx.y * 32;
  const int tx = threadIdx.x, ty = threadIdx.y;
#pragma unroll
  for (int i = 0; i < 32; i += 8)
    tile[ty + i][tx] = Wz[(size_t)(y0 + ty + i) * 1024 + x0 + tx];
  __syncthreads();
#pragma unroll
  for (int i = 0; i < 32; i += 8)
    Wtz[(size_t)(x0 + ty + i) * 1024 + y0 + tx] = f2bf(tile[tx][ty + i]);
}

// ---------- GEMM: C[m,n] = scale * sum_k A[m,k] * Bt[n,k] ----------
// A: [M,K] bf16 row-major, Bt: [N,K] bf16 row-major. Tiles 128x128x32.
// 256 threads = 4 waves in 2x2. MODE: 0 = bf16 store (w/ scale), 2 = Vt-transposed
// bf16 store (V path, m = b*2048+s -> Vt[b][n][s]), 3 = f32 store.
template <int MODE>
__global__ void __launch_bounds__(256)
gemm_bt(const unsigned short* __restrict__ Aall,
        const unsigned short* __restrict__ Btall,
        void* __restrict__ Call,
        int K, int ldc, long sA, long sB, long sC, float scale) {
  __shared__ unsigned short As[128 * 32];
  __shared__ unsigned short Bs[128 * 32];
  const int t = threadIdx.x;
  const int lane = t & 63;
  const int quad = lane >> 4;
  const int l15 = lane & 15;
  const int wave = t >> 6;
  const int wm = (wave >> 1) * 64;
  const int wn = (wave & 1) * 64;
  const int z = blockIdx.z;

  const unsigned short* A = Aall + (size_t)z * sA + (size_t)blockIdx.x * 128 * K;
  const unsigned short* Bt = Btall + (size_t)z * sB + (size_t)blockIdx.y * 128 * K;

  // staging: byte f = t*16 + i*4096 of the 8KB tile; row = f/64, col = (f%64)/2
  const int srow = t >> 2;
  const int scol = (t & 3) * 8;
  const unsigned short* ga0 = A + (size_t)srow * K + scol;
  const unsigned short* ga1 = A + (size_t)(srow + 64) * K + scol;
  const unsigned short* gb0 = Bt + (size_t)srow * K + scol;
  const unsigned short* gb1 = Bt + (size_t)(srow + 64) * K + scol;
  unsigned short* lA0 = As + t * 8;
  unsigned short* lA1 = As + t * 8 + 2048;
  unsigned short* lB0 = Bs + t * 8;
  unsigned short* lB1 = Bs + t * 8 + 2048;

  const unsigned short* aP = As + (wm + l15) * 32 + quad * 8;
  const unsigned short* bP = Bs + (wn + l15) * 32 + quad * 8;

  f32x4 acc[4][4];
#pragma unroll
  for (int i = 0; i < 4; i++)
#pragma unroll
    for (int j = 0; j < 4; j++) acc[i][j] = (f32x4){0.f, 0.f, 0.f, 0.f};

  for (int k0 = 0; k0 < K; k0 += 32) {
    gload_lds16(ga0 + k0, lA0);
    gload_lds16(ga1 + k0, lA1);
    gload_lds16(gb0 + k0, lB0);
    gload_lds16(gb1 + k0, lB1);
    __syncthreads();
    bf16x8 a[4], b[4];
#pragma unroll
    for (int i = 0; i < 4; i++) a[i] = *(const bf16x8*)(aP + i * 512);
#pragma unroll
    for (int i = 0; i < 4; i++) b[i] = *(const bf16x8*)(bP + i * 512);
#pragma unroll
    for (int i = 0; i < 4; i++)
#pragma unroll
      for (int j = 0; j < 4; j++)
        acc[i][j] = __builtin_amdgcn_mfma_f32_16x16x32_bf16(a[i], b[j], acc[i][j], 0, 0, 0);
    __syncthreads();
  }

  // C/D layout: col = lane&15, row = quad*4 + reg  [verified m89/m91]
  const int mbase = blockIdx.x * 128 + wm + quad * 4;
  const int nbase = blockIdx.y * 128 + wn + l15;

  if (MODE == 0) {
    unsigned short* C = (unsigned short*)Call + (size_t)z * sC;
#pragma unroll
    for (int mi = 0; mi < 4; mi++)
#pragma unroll
      for (int ni = 0; ni < 4; ni++) {
        const int m = mbase + mi * 16, n = nbase + ni * 16;
#pragma unroll
        for (int r = 0; r < 4; r++)
          C[(size_t)(m + r) * ldc + n] = f2bf(acc[mi][ni][r] * scale);
      }
  } else if (MODE == 3) {
    float* C = (float*)Call + (size_t)z * sC;
#pragma unroll
    for (int mi = 0; mi < 4; mi++)
#pragma unroll
      for (int ni = 0; ni < 4; ni++) {
        const int m = mbase + mi * 16, n = nbase + ni * 16;
#pragma unroll
        for (int r = 0; r < 4; r++)
          C[(size_t)(m + r) * ldc + n] = acc[mi][ni][r];
      }
  } else {  // MODE 2: Vt[b][e=n][s] <- acc, m = b*2048 + s; 4 consecutive s -> 8B store
    unsigned short* C = (unsigned short*)Call;
#pragma unroll
    for (int mi = 0; mi < 4; mi++) {
      const int m = mbase + mi * 16;
      const int b = m >> 11, s = m & 2047;
#pragma unroll
      for (int ni = 0; ni < 4; ni++) {
        const int n = nbase + ni * 16;
        uint2 val;
        val.x = (uint32_t)f2bf(acc[mi][ni][0]) | ((uint32_t)f2bf(acc[mi][ni][1]) << 16);
        val.y = (uint32_t)f2bf(acc[mi][ni][2]) | ((uint32_t)f2bf(acc[mi][ni][3]) << 16);
        *(uint2*)(C + (size_t)b * 2097152 + (size_t)n * 2048 + s) = val;
      }
    }
  }
}

// ---------- row softmax, in place, bf16 [rows=8192, len=2048] ----------
__global__ void softmax_kernel(unsigned short* __restrict__ S) {
  __shared__ float redmax[4];
  __shared__ float redsum[4];
  const size_t row = blockIdx.x;
  unsigned short* p = S + row * 2048;
  const int t = threadIdx.x;
  uint4 raw = *(const uint4*)(p + t * 8);
  const unsigned short* up = (const unsigned short*)&raw;
  float v[8];
#pragma unroll
  for (int i = 0; i < 8; i++) v[i] = bf2f(up[i]);
  float m = v[0];
#pragma unroll
  for (int i = 1; i < 8; i++) m = fmaxf(m, v[i]);
#pragma unroll
  for (int off = 32; off > 0; off >>= 1) m = fmaxf(m, __shfl_xor(m, off));
  if ((t & 63) == 0) redmax[t >> 6] = m;
  __syncthreads();
  m = fmaxf(fmaxf(redmax[0], redmax[1]), fmaxf(redmax[2], redmax[3]));
  float s = 0.f;
#pragma unroll
  for (int i = 0; i < 8; i++) { v[i] = __expf(v[i] - m); s += v[i]; }
#pragma unroll
  for (int off = 32; off > 0; off >>= 1) s += __shfl_xor(s, off);
  if ((t & 63) == 0) redsum[t >> 6] = s;
  __syncthreads();
  s = redsum[0] + redsum[1] + redsum[2] + redsum[3];
  const float inv = 1.f / s;
  uint4 o;
  o.x = (uint32_t)f2bf(v[0] * inv) | ((uint32_t)f2bf(v[1] * inv) << 16);
  o.y = (uint32_t)f2bf(v[2] * inv) | ((uint32_t)f2bf(v[3] * inv) << 16);
  o.z = (uint32_t)f2bf(v[4] * inv) | ((uint32_t)f2bf(v[5] * inv) << 16);
  o.w = (uint32_t)f2bf(v[6] * inv) | ((uint32_t)f2bf(v[7] * inv) << 16);
  *(uint4*)(p + t * 8) = o;
}

// ---------- launcher ----------
// B=4, S=2048, D=1024. Workspace layout (bytes):
//   xb  @ 0     : 16 MB  bf16 x        [8192,1024]
//   Wt  @ 16MB  : 6  MB  bf16 W^T      [3][e][d]
//   Q   @ 22MB  : 16 MB  bf16          [8192,1024]
//   K   @ 38MB  : 16 MB  bf16          [8192,1024]
//   Vt  @ 54MB  : 16 MB  bf16          [4][e=1024][s=2048]
//   Sb  @ 70MB  : 32 MB  bf16 scores/P [4][2048][2048]
// total 102 MB.
extern "C" void kernel_launch(void* const* d_in, const int* in_sizes, int n_in,
                              void* d_out, int out_size, void* d_ws, size_t ws_size,
                              hipStream_t stream) {
  const float* x = (const float*)d_in[0];
  const float* W = (const float*)d_in[1];
  float* out = (float*)d_out;
  char* ws = (char*)d_ws;
  unsigned short* xb = (unsigned short*)(ws);
  unsigned short* Wt = (unsigned short*)(ws + (16ll << 20));
  unsigned short* Q  = (unsigned short*)(ws + (22ll << 20));
  unsigned short* Kb = (unsigned short*)(ws + (38ll << 20));
  unsigned short* Vt = (unsigned short*)(ws + (54ll << 20));
  unsigned short* Sb = (unsigned short*)(ws + (70ll << 20));

  cast_x_kernel<<<4096, 256, 0, stream>>>(x, xb);
  cast_w_kernel<<<dim3(32, 32, 3), dim3(32, 8), 0, stream>>>(W, Wt);

  // Q and K projections: z=0 -> Q, z=1 -> K (contiguous buffers, stride 8M elems)
  gemm_bt<0><<<dim3(64, 8, 2), 256, 0, stream>>>(
      xb, Wt, Q, 1024, 1024, 0L, 1048576L, 8388608L, 1.0f);
  // V projection with transposed store -> Vt
  gemm_bt<2><<<dim3(64, 8, 1), 256, 0, stream>>>(
      xb, Wt + 2 * 1048576, Vt, 1024, 0, 0L, 0L, 0L, 1.0f);
  // scores = Q K^T / 32, bf16, per batch
  gemm_bt<0><<<dim3(16, 16, 4), 256, 0, stream>>>(
      Q, Kb, Sb, 1024, 2048, 2097152L, 2097152L, 4194304L, 0.03125f);
  // softmax rows in place
  softmax_kernel<<<8192, 256, 0, stream>>>(Sb);
  // out = P @ V  (fp32 store to d_out)
  gemm_bt<3><<<dim3(16, 8, 4), 256, 0, stream>>>(
      Sb, Vt, out, 2048, 1024, 4194304L, 2097152L, 2097152L, 1.0f);
}

// Round 2
// 270.211 us; speedup vs baseline: 1.1075x; 1.1075x over previous
//
#include <hip/hip_runtime.h>
#include <hip/hip_bf16.h>
#include <cstdint>

typedef __bf16 bf16x8 __attribute__((ext_vector_type(8)));
typedef float f32x4 __attribute__((ext_vector_type(4)));

// ---------- helpers ----------
__device__ __forceinline__ unsigned short f2bf(float f) {
  union { float f; uint32_t u; } a; a.f = f;
  uint32_t r = a.u + 0x7fffu + ((a.u >> 16) & 1u);
  return (unsigned short)(r >> 16);
}
__device__ __forceinline__ float bf2f(unsigned short b) {
  union { uint32_t u; float f; } a; a.u = ((uint32_t)b) << 16;
  return a.f;
}
__device__ __forceinline__ void gload_lds16(const unsigned short* g, unsigned short* l) {
  __builtin_amdgcn_global_load_lds(
      (const __attribute__((address_space(1))) void*)g,
      (__attribute__((address_space(3))) void*)l, 16, 0, 0);
}

// ---------- cast kernels ----------
// x: 8,388,608 fp32 -> bf16. 8 elems/thread, grid 4096 x 256.
__global__ void cast_x_kernel(const float* __restrict__ x, unsigned short* __restrict__ xb) {
  size_t i = ((size_t)blockIdx.x * 256 + threadIdx.x) * 8;
  float4 a = *(const float4*)(x + i);
  float4 b = *(const float4*)(x + i + 4);
  uint4 o;
  o.x = (uint32_t)f2bf(a.x) | ((uint32_t)f2bf(a.y) << 16);
  o.y = (uint32_t)f2bf(a.z) | ((uint32_t)f2bf(a.w) << 16);
  o.z = (uint32_t)f2bf(b.x) | ((uint32_t)f2bf(b.y) << 16);
  o.w = (uint32_t)f2bf(b.z) | ((uint32_t)f2bf(b.w) << 16);
  *(uint4*)(xb + i) = o;
}

// W[3][1024][1024] fp32 -> Wt[3][e][d] bf16 (transpose last two dims).
// grid (32,32,3), block (32,8)
__global__ void cast_w_kernel(const float* __restrict__ W, unsigned short* __restrict__ Wt) {
  __shared__ float tile[32][33];
  const int z = blockIdx.z;
  const float* Wz = W + (size_t)z * 1024 * 1024;
  unsigned short* Wtz = Wt + (size_t)z * 1024 * 1024;
  const int x0 = blockIdx.x * 32, y0 = blockIdx.y * 32;
  const int tx = threadIdx.x, ty = threadIdx.y;
#pragma unroll
  for (int i = 0; i < 32; i += 8)
    tile[ty + i][tx] = Wz[(size_t)(y0 + ty + i) * 1024 + x0 + tx];
  __syncthreads();
#pragma unroll
  for (int i = 0; i < 32; i += 8)
    Wtz[(size_t)(x0 + ty + i) * 1024 + y0 + tx] = f2bf(tile[tx][ty + i]);
}

// ---------- GEMM: C[m,n] = scale * sum_k A[m,k] * Bt[n,k] ----------
// A: [M,K] bf16 row-major, Bt: [N,K] bf16 row-major. Tiles 128x128, BK=64.
// LDS tile: [row 0..127][chunk 0..7] of 16B chunks, XOR-swizzled:
//   LDS(row, c) = global chunk (c ^ (row&7)) of that row  -> conflict-free
//   ds_read_b128 AND legal global_load_lds (source-side permutation).
// 256 threads = 4 waves in 2x2. MODE: 0 = bf16 store (w/ scale), 2 = Vt-transposed
// bf16 store (V path, m = b*2048+s -> Vt[b][n][s]), 3 = f32 store.
template <int MODE>
__global__ void __launch_bounds__(256)
gemm_bt(const unsigned short* __restrict__ Aall,
        const unsigned short* __restrict__ Btall,
        void* __restrict__ Call,
        int K, int ldc, long sA, long sB, long sC, float scale) {
  __shared__ unsigned short As[128 * 64];
  __shared__ unsigned short Bs[128 * 64];
  const int t = threadIdx.x;
  const int lane = t & 63;
  const int quad = lane >> 4;
  const int l15 = lane & 15;
  const int wave = t >> 6;
  const int wm = (wave >> 1) * 64;
  const int wn = (wave & 1) * 64;
  const int z = blockIdx.z;

  const unsigned short* A = Aall + (size_t)z * sA + (size_t)blockIdx.x * 128 * K;
  const unsigned short* Bt = Btall + (size_t)z * sB + (size_t)blockIdx.y * 128 * K;

  // staging: thread t -> LDS row (i*32 + t>>3), chunk (t&7).
  // source chunk is swizzled: (t&7) ^ (row&7), row&7 == (t>>3)&7.
  const int srow = t >> 3;                       // 0..31
  const int scol = ((t & 7) ^ (srow & 7)) * 8;   // element offset in row
  const unsigned short* ga = A + (size_t)srow * K + scol;
  const unsigned short* gb = Bt + (size_t)srow * K + scol;
  unsigned short* lA = As + t * 8;
  unsigned short* lB = Bs + t * 8;

  // fragment read: row = w? + 16i + l15, chunk_h = (quad ^ 4h) ^ (l15&7)
  const int c0 = (quad ^ (l15 & 7)) * 8;         // ushort offset, h=0
  const unsigned short* aP = As + (size_t)(wm + l15) * 64;
  const unsigned short* bP = Bs + (size_t)(wn + l15) * 64;

  f32x4 acc[4][4];
#pragma unroll
  for (int i = 0; i < 4; i++)
#pragma unroll
    for (int j = 0; j < 4; j++) acc[i][j] = (f32x4){0.f, 0.f, 0.f, 0.f};

  for (int k0 = 0; k0 < K; k0 += 64) {
#pragma unroll
    for (int i = 0; i < 4; i++) {
      gload_lds16(ga + (size_t)i * 32 * K + k0, lA + i * 2048);
      gload_lds16(gb + (size_t)i * 32 * K + k0, lB + i * 2048);
    }
    __syncthreads();
#pragma unroll
    for (int h = 0; h < 2; h++) {
      const int co = c0 ^ (h * 32);  // (chunk0 ^ 4h) * 8 ushorts
      bf16x8 a[4], b[4];
#pragma unroll
      for (int i = 0; i < 4; i++) a[i] = *(const bf16x8*)(aP + i * 1024 + co);
#pragma unroll
      for (int j = 0; j < 4; j++) b[j] = *(const bf16x8*)(bP + j * 1024 + co);
#pragma unroll
      for (int i = 0; i < 4; i++)
#pragma unroll
        for (int j = 0; j < 4; j++)
          acc[i][j] = __builtin_amdgcn_mfma_f32_16x16x32_bf16(a[i], b[j], acc[i][j], 0, 0, 0);
    }
    __syncthreads();
  }

  // C/D layout: col = lane&15, row = quad*4 + reg  [verified m89/m91]
  const int mbase = blockIdx.x * 128 + wm + quad * 4;
  const int nbase = blockIdx.y * 128 + wn + l15;

  if (MODE == 0) {
    unsigned short* C = (unsigned short*)Call + (size_t)z * sC;
#pragma unroll
    for (int mi = 0; mi < 4; mi++)
#pragma unroll
      for (int ni = 0; ni < 4; ni++) {
        const int m = mbase + mi * 16, n = nbase + ni * 16;
#pragma unroll
        for (int r = 0; r < 4; r++)
          C[(size_t)(m + r) * ldc + n] = f2bf(acc[mi][ni][r] * scale);
      }
  } else if (MODE == 3) {
    float* C = (float*)Call + (size_t)z * sC;
#pragma unroll
    for (int mi = 0; mi < 4; mi++)
#pragma unroll
      for (int ni = 0; ni < 4; ni++) {
        const int m = mbase + mi * 16, n = nbase + ni * 16;
#pragma unroll
        for (int r = 0; r < 4; r++)
          C[(size_t)(m + r) * ldc + n] = acc[mi][ni][r];
      }
  } else {  // MODE 2: Vt[b][e=n][s] <- acc, m = b*2048 + s; 4 consecutive s -> 8B store
    unsigned short* C = (unsigned short*)Call;
#pragma unroll
    for (int mi = 0; mi < 4; mi++) {
      const int m = mbase + mi * 16;
      const int b = m >> 11, s = m & 2047;
#pragma unroll
      for (int ni = 0; ni < 4; ni++) {
        const int n = nbase + ni * 16;
        uint2 val;
        val.x = (uint32_t)f2bf(acc[mi][ni][0]) | ((uint32_t)f2bf(acc[mi][ni][1]) << 16);
        val.y = (uint32_t)f2bf(acc[mi][ni][2]) | ((uint32_t)f2bf(acc[mi][ni][3]) << 16);
        *(uint2*)(C + (size_t)b * 2097152 + (size_t)n * 2048 + s) = val;
      }
    }
  }
}

// ---------- row softmax, in place, bf16 [rows=8192, len=2048] ----------
__global__ void softmax_kernel(unsigned short* __restrict__ S) {
  __shared__ float redmax[4];
  __shared__ float redsum[4];
  const size_t row = blockIdx.x;
  unsigned short* p = S + row * 2048;
  const int t = threadIdx.x;
  uint4 raw = *(const uint4*)(p + t * 8);
  const unsigned short* up = (const unsigned short*)&raw;
  float v[8];
#pragma unroll
  for (int i = 0; i < 8; i++) v[i] = bf2f(up[i]);
  float m = v[0];
#pragma unroll
  for (int i = 1; i < 8; i++) m = fmaxf(m, v[i]);
#pragma unroll
  for (int off = 32; off > 0; off >>= 1) m = fmaxf(m, __shfl_xor(m, off));
  if ((t & 63) == 0) redmax[t >> 6] = m;
  __syncthreads();
  m = fmaxf(fmaxf(redmax[0], redmax[1]), fmaxf(redmax[2], redmax[3]));
  float s = 0.f;
#pragma unroll
  for (int i = 0; i < 8; i++) { v[i] = __expf(v[i] - m); s += v[i]; }
#pragma unroll
  for (int off = 32; off > 0; off >>= 1) s += __shfl_xor(s, off);
  if ((t & 63) == 0) redsum[t >> 6] = s;
  __syncthreads();
  s = redsum[0] + redsum[1] + redsum[2] + redsum[3];
  const float inv = 1.f / s;
  uint4 o;
  o.x = (uint32_t)f2bf(v[0] * inv) | ((uint32_t)f2bf(v[1] * inv) << 16);
  o.y = (uint32_t)f2bf(v[2] * inv) | ((uint32_t)f2bf(v[3] * inv) << 16);
  o.z = (uint32_t)f2bf(v[4] * inv) | ((uint32_t)f2bf(v[5] * inv) << 16);
  o.w = (uint32_t)f2bf(v[6] * inv) | ((uint32_t)f2bf(v[7] * inv) << 16);
  *(uint4*)(p + t * 8) = o;
}

// ---------- launcher ----------
// B=4, S=2048, D=1024. Workspace layout (bytes):
//   xb  @ 0     : 16 MB  bf16 x        [8192,1024]
//   Wt  @ 16MB  : 6  MB  bf16 W^T      [3][e][d]
//   Q   @ 22MB  : 16 MB  bf16          [8192,1024]
//   K   @ 38MB  : 16 MB  bf16          [8192,1024]
//   Vt  @ 54MB  : 16 MB  bf16          [4][e=1024][s=2048]
//   Sb  @ 70MB  : 32 MB  bf16 scores/P [4][2048][2048]
// total 102 MB.
extern "C" void kernel_launch(void* const* d_in, const int* in_sizes, int n_in,
                              void* d_out, int out_size, void* d_ws, size_t ws_size,
                              hipStream_t stream) {
  const float* x = (const float*)d_in[0];
  const float* W = (const float*)d_in[1];
  float* out = (float*)d_out;
  char* ws = (char*)d_ws;
  unsigned short* xb = (unsigned short*)(ws);
  unsigned short* Wt = (unsigned short*)(ws + (16ll << 20));
  unsigned short* Q  = (unsigned short*)(ws + (22ll << 20));
  unsigned short* Kb = (unsigned short*)(ws + (38ll << 20));
  unsigned short* Vt = (unsigned short*)(ws + (54ll << 20));
  unsigned short* Sb = (unsigned short*)(ws + (70ll << 20));

  cast_x_kernel<<<4096, 256, 0, stream>>>(x, xb);
  cast_w_kernel<<<dim3(32, 32, 3), dim3(32, 8), 0, stream>>>(W, Wt);

  // Q and K projections: z=0 -> Q, z=1 -> K (contiguous buffers, stride 8M elems)
  gemm_bt<0><<<dim3(64, 8, 2), 256, 0, stream>>>(
      xb, Wt, Q, 1024, 1024, 0L, 1048576L, 8388608L, 1.0f);
  // V projection with transposed store -> Vt
  gemm_bt<2><<<dim3(64, 8, 1), 256, 0, stream>>>(
      xb, Wt + 2 * 1048576, Vt, 1024, 0, 0L, 0L, 0L, 1.0f);
  // scores = Q K^T / 32, bf16, per batch
  gemm_bt<0><<<dim3(16, 16, 4), 256, 0, stream>>>(
      Q, Kb, Sb, 1024, 2048, 2097152L, 2097152L, 4194304L, 0.03125f);
  // softmax rows in place
  softmax_kernel<<<8192, 256, 0, stream>>>(Sb);
  // out = P @ V  (fp32 store to d_out)
  gemm_bt<3><<<dim3(16, 8, 4), 256, 0, stream>>>(
      Sb, Vt, out, 2048, 1024, 4194304L, 2097152L, 2097152L, 1.0f);
}